// Round 1
// 410.995 us; speedup vs baseline: 1.0158x; 1.0158x over previous
//
#include <hip/hip_runtime.h>

#define BS 7
#define DROPP 0.1f
#define UH 58
#define UW 58

typedef float f32x4 __attribute__((ext_vector_type(4)));  // native vec: OK for nontemporal builtins

// One block. Bitmask dilation: row i of drop -> 64-bit word; 7x7 max-dilate =
// OR of 7 shifted words (row) then OR of <=7 rows (col). keep-count via popcount.
__global__ __launch_bounds__(1024) void dropblock_mask_kernel(
    const float* __restrict__ u, float* __restrict__ m)
{
    __shared__ unsigned long long sD[64];    // per-row drop bits (rows >=58 zero)
    __shared__ unsigned long long sR[64];    // row-dilated
    __shared__ unsigned long long sDil[64];  // fully dilated
    __shared__ float sscale;

    const int tid  = threadIdx.x;
    const int wave = tid >> 6;   // 0..15
    const int lane = tid & 63;

    // Phase 1: wave w builds rows w, w+16, w+32, w+48 via ballot
    for (int i = wave; i < 64; i += 16) {
        bool d = false;
        if (i < UH && lane < UW) d = (u[i * UW + lane] < DROPP);
        unsigned long long D = __ballot(d);
        if (lane == 0) sD[i] = D;
    }
    __syncthreads();

    // Phase 2: wave 0, lane i: row dilation (6 shifts+ORs)
    if (wave == 0) {
        unsigned long long D = sD[lane];
        unsigned long long R = D;
        #pragma unroll
        for (int s = 1; s <= 6; ++s) R |= (D << s);
        sR[lane] = R;
    }
    __syncthreads();

    // Phase 3: wave 0, lane y: column dilation + popcount + wave-reduce sum
    if (wave == 0) {
        const int y = lane;
        const int i0 = (y - 6 > 0) ? (y - 6) : 0;
        const int i1 = (y < UH - 1) ? y : (UH - 1);
        unsigned long long dil = 0ull;
        for (int i = i0; i <= i1; ++i) dil |= sR[i];
        sDil[y] = dil;
        float kept = (float)(64 - __popcll(dil));
        #pragma unroll
        for (int off = 32; off >= 1; off >>= 1)
            kept += __shfl_down(kept, off, 64);
        if (lane == 0) sscale = 4096.0f / kept;
    }
    __syncthreads();

    // Phase 4: all 1024 threads emit m as one float4 each (coalesced)
    const float s = sscale;
    const unsigned long long dil = sDil[(tid >> 4) & 63]; // y = (4*tid)>>6
    const int xb = (tid * 4) & 63;                        // <= 60, same word
    f32x4 mv;
    mv.x = ((dil >> (xb + 0)) & 1ull) ? 0.0f : s;
    mv.y = ((dil >> (xb + 1)) & 1ull) ? 0.0f : s;
    mv.z = ((dil >> (xb + 2)) & 1ull) ? 0.0f : s;
    mv.w = ((dil >> (xb + 3)) & 1ull) ? 0.0f : s;
    ((f32x4*)m)[tid] = mv;
}

// HBM-bound streaming multiply — but the mask is ~94% zeros (interior keep
// prob = 0.9^49), shared across all N*C planes. Where the float4's mask word
// is all-zero, the output is exactly 0 and x NEED NOT BE READ. Lane-level
// predication -> skipped lanes issue no VMEM request; fully-dropped row spans
// let whole waves skip via s_cbranch_execz. Read traffic: 256 MiB -> ~kept
// fraction (line-granularity inflated). Write (256 MiB, nontemporal) is the
// irreducible floor.
__global__ __launch_bounds__(256) void dropblock_apply_kernel(
    const f32x4* __restrict__ x, const f32x4* __restrict__ m4,
    f32x4* __restrict__ out)
{
    const int gid = blockIdx.x * 256 + threadIdx.x;
    const f32x4 mv = m4[gid & 1023];   // 16 KiB plane, L1/L2-resident
    f32x4 ov = {0.0f, 0.0f, 0.0f, 0.0f};
    // mask entries are 0.0f or +s: bitwise-OR test is exact
    union { f32x4 f; unsigned int b[4]; } mu; mu.f = mv;
    if ((mu.b[0] | mu.b[1] | mu.b[2] | mu.b[3]) != 0u) {
        const f32x4 xv = __builtin_nontemporal_load(&x[gid]);
        ov = xv * mv;
    }
    __builtin_nontemporal_store(ov, &out[gid]);
}

extern "C" void kernel_launch(void* const* d_in, const int* in_sizes, int n_in,
                              void* d_out, int out_size, void* d_ws, size_t ws_size,
                              hipStream_t stream) {
    const float* x = (const float*)d_in[0];   // [64,256,64,64] fp32
    const float* u = (const float*)d_in[1];   // [58,58] fp32
    float* out = (float*)d_out;
    float* m   = (float*)d_ws;                // 4096 floats scratch

    dropblock_mask_kernel<<<1, 1024, 0, stream>>>(u, m);

    const int total4 = out_size / 4;          // 16,777,216 float4s
    dropblock_apply_kernel<<<total4 / 256, 256, 0, stream>>>(
        (const f32x4*)x, (const f32x4*)m, (f32x4*)out);
}